// Round 4
// baseline (125.340 us; speedup 1.0000x reference)
//
#include <hip/hip_runtime.h>
#include <hip/hip_fp16.h>
#include <math.h>

// Problem constants (reference: B=8, N=16384, K=32)
#define PB 8
#define PN 16384
#define PK 32
#define PEPS 1e-5f

// ---------- full-rate quad DPP reduction (4-lane groups) -------------------
// quad_perm xor1 = [1,0,3,2] -> ctrl 0xB1 ; xor2 = [2,3,0,1] -> ctrl 0x4E.
// After both steps every lane of the quad holds the 4-lane sum.
template <int CTRL>
__device__ __forceinline__ float quad_add_step(float v) {
    int t = __builtin_amdgcn_update_dpp(0, __float_as_int(v), CTRL, 0xf, 0xf, true);
    return v + __int_as_float(t);
}
__device__ __forceinline__ float quad_reduce(float v) {
    v = quad_add_step<0xB1>(v);   // xor 1
    v = quad_add_step<0x4E>(v);   // xor 2
    return v;
}

// ---------------- pre-pass: pack xyz + intensity into 16B fp16 records -----
// packed[b*N+n] = halves {x, y, z, 0, i0, i1, i2, 0}   (one uint4)
// Thread 0 additionally folds BN into affine constants at cst[0..15].
__global__ __launch_bounds__(256) void sa_pack(
    const float* __restrict__ xyz,        // [B,N,3]
    const float* __restrict__ intensity,  // [B,3,N]
    uint4* __restrict__ packed,           // [B*N]
    const float* __restrict__ w1, const float* __restrict__ b1,
    const float* __restrict__ gamma_, const float* __restrict__ beta_,
    const float* __restrict__ mean_, const float* __restrict__ var_,
    const float* __restrict__ w2, const float* __restrict__ b2,
    float* __restrict__ cst)              // [16]
{
    const int t = blockIdx.x * 256 + threadIdx.x;   // 0..B*N-1
    const int b = t >> 14;                          // N = 2^14
    const int n = t & (PN - 1);
    const float x = xyz[(long)t * 3 + 0];
    const float y = xyz[(long)t * 3 + 1];
    const float z = xyz[(long)t * 3 + 2];
    const float* ib = intensity + (long)b * 3 * PN;
    const float i0 = ib[0 * PN + n];
    const float i1 = ib[1 * PN + n];
    const float i2 = ib[2 * PN + n];

    union { __half2 h2[4]; uint4 u; } rec;
    rec.h2[0] = __halves2half2(__float2half_rn(x), __float2half_rn(y));
    rec.h2[1] = __halves2half2(__float2half_rn(z), __float2half_rn(0.f));
    rec.h2[2] = __halves2half2(__float2half_rn(i0), __float2half_rn(i1));
    rec.h2[3] = __halves2half2(__float2half_rn(i2), __float2half_rn(0.f));
    packed[t] = rec.u;

    if (t == 0) {
        for (int o = 0; o < 3; ++o) {
            const float sc = gamma_[o] * rsqrtf(var_[o] + PEPS);
            for (int c = 0; c < 3; ++c) cst[o * 3 + c] = w1[o * 3 + c] * sc;
            cst[9 + o]  = (b1[o] - mean_[o]) * sc + beta_[o];
            cst[12 + o] = w2[o];
        }
        cst[15] = b2[0];
    }
}

// ---------------- main: 4 lanes per point, 8 neighbors per lane ------------
__global__ __launch_bounds__(256) void sa_main4(
    const uint4* __restrict__ packed,     // [B*N] fp16 records
    const int*   __restrict__ indices,    // [B,N,K]
    const float* __restrict__ cst,        // [16] folded constants
    float* __restrict__ out)              // [B,3,N]
{
    const int t = blockIdx.x * 256 + threadIdx.x;  // global lane id
    const int q = t >> 2;                          // point id 0..B*N-1
    const int l = t & 3;                           // quad lane -> neighbors l*8..l*8+7
    const int b = q >> 14;
    const int n = q & (PN - 1);

    // folded constants (uniform -> scalar loads)
    const float A00 = cst[0], A01 = cst[1], A02 = cst[2];
    const float A10 = cst[3], A11 = cst[4], A12 = cst[5];
    const float A20 = cst[6], A21 = cst[7], A22 = cst[8];
    const float d0 = cst[9], d1 = cst[10], d2 = cst[11];
    const float w0 = cst[12], w1v = cst[13], w2v = cst[14];
    const float bias2 = cst[15];

    // center record (quad-uniform address; wave touches ~4 consecutive lines)
    const uint4 c = packed[q];
    const float2 cxy = __half22float2(*(const __half2*)&c.x);
    const float  cz  = __half2float(*(const __half*)&c.y);

    // 8 neighbor indices for this lane: two coalesced int4 loads
    const int4* ip = (const int4*)(indices + (long)q * PK + l * 8);
    const int4 i0v = ip[0];
    const int4 i1v = ip[1];
    int idxs[8] = { i0v.x, i0v.y, i0v.z, i0v.w, i1v.x, i1v.y, i1v.z, i1v.w };

    // issue all 8 divergent gathers up front (memory ILP)
    uint4 rec[8];
#pragma unroll
    for (int j = 0; j < 8; ++j) rec[j] = packed[(b << 14) | idxs[j]];

    float s = 0.f, a0 = 0.f, a1 = 0.f, a2 = 0.f;
#pragma unroll
    for (int j = 0; j < 8; ++j) {
        const uint4 r = rec[j];
        const float2 nxy  = __half22float2(*(const __half2*)&r.x);
        const float  nz   = __half2float(*(const __half*)&r.y);
        const float2 ni01 = __half22float2(*(const __half2*)&r.z);
        const float  ni2  = __half2float(*(const __half*)&r.w);

        const float px = nxy.x - cxy.x;
        const float py = nxy.y - cxy.y;
        const float pz = nz - cz;

        const float g0 = __expf(-2.f * px * px);
        const float g1 = __expf(-2.f * py * py);
        const float g2 = __expf(-2.f * pz * pz);

        float h0 = fmaf(A00, g0, fmaf(A01, g1, fmaf(A02, g2, d0)));
        float h1 = fmaf(A10, g0, fmaf(A11, g1, fmaf(A12, g2, d1)));
        float h2 = fmaf(A20, g0, fmaf(A21, g1, fmaf(A22, g2, d2)));
        h0 = fmaxf(h0, 0.f); h1 = fmaxf(h1, 0.f); h2 = fmaxf(h2, 0.f);
        const float logit = fmaf(w0, h0, fmaf(w1v, h1, fmaf(w2v, h2, bias2)));

        // logits bounded by the tiny folded weights -> no max-subtraction
        const float e = __expf(logit);
        s += e;
        a0 = fmaf(e, ni01.x, a0);
        a1 = fmaf(e, ni01.y, a1);
        a2 = fmaf(e, ni2,    a2);
    }

    // 4-lane tree sums; afterwards every quad lane holds the totals
    s  = quad_reduce(s);
    a0 = quad_reduce(a0);
    a1 = quad_reduce(a1);
    a2 = quad_reduce(a2);

    if (l < 3) {
        const float val = (l == 0) ? a0 : ((l == 1) ? a1 : a2);
        out[(long)b * 3 * PN + l * PN + n] = val * (1.f / s);
    }
}

// ---------------- fallback (no workspace): round-1 kernel -----------------
__global__ __launch_bounds__(256) void sa_fallback(
    const float* __restrict__ xyz, const float* __restrict__ intensity,
    const int* __restrict__ indices,
    const float* __restrict__ w1, const float* __restrict__ b1,
    const float* __restrict__ gamma_, const float* __restrict__ beta_,
    const float* __restrict__ mean_, const float* __restrict__ var_,
    const float* __restrict__ w2, const float* __restrict__ b2,
    float* __restrict__ out)
{
    const int lane = threadIdx.x & 31;
    const int grp  = threadIdx.x >> 5;
    const long ng  = (long)blockIdx.x * 8 + grp;
    const int b = (int)(ng >> 14);
    const int n = (int)(ng & (PN - 1));

    float A[3][3], d[3], wv[3];
#pragma unroll
    for (int o = 0; o < 3; ++o) {
        const float sc = gamma_[o] * rsqrtf(var_[o] + PEPS);
#pragma unroll
        for (int c = 0; c < 3; ++c) A[o][c] = w1[o * 3 + c] * sc;
        d[o]  = (b1[o] - mean_[o]) * sc + beta_[o];
        wv[o] = w2[o];
    }
    const float bias2 = b2[0];
    const long bn = (long)b * PN + n;
    const float cx = xyz[bn * 3 + 0], cy = xyz[bn * 3 + 1], cz = xyz[bn * 3 + 2];
    const int idx = indices[bn * PK + lane];
    const long bi = (long)b * PN + idx;
    const float px = xyz[bi * 3 + 0] - cx;
    const float py = xyz[bi * 3 + 1] - cy;
    const float pz = xyz[bi * 3 + 2] - cz;
    const float g0 = __expf(-2.f * px * px);
    const float g1 = __expf(-2.f * py * py);
    const float g2 = __expf(-2.f * pz * pz);
    float logit = bias2;
#pragma unroll
    for (int o = 0; o < 3; ++o) {
        float h = A[o][0] * g0 + A[o][1] * g1 + A[o][2] * g2 + d[o];
        h = fmaxf(h, 0.f);
        logit = fmaf(wv[o], h, logit);
    }
    float m = logit;
#pragma unroll
    for (int s = 16; s > 0; s >>= 1) m = fmaxf(m, __shfl_xor(m, s, 64));
    const float e = __expf(logit - m);
    const float* ib = intensity + (long)b * 3 * PN;
    float ssum = e;
    float a0 = e * ib[0 * PN + idx];
    float a1 = e * ib[1 * PN + idx];
    float a2 = e * ib[2 * PN + idx];
#pragma unroll
    for (int s = 16; s > 0; s >>= 1) {
        ssum += __shfl_xor(ssum, s, 64);
        a0 += __shfl_xor(a0, s, 64);
        a1 += __shfl_xor(a1, s, 64);
        a2 += __shfl_xor(a2, s, 64);
    }
    if (lane == 0) {
        const float inv = 1.f / ssum;
        float* ob = out + (long)b * 3 * PN;
        ob[0 * PN + n] = a0 * inv;
        ob[1 * PN + n] = a1 * inv;
        ob[2 * PN + n] = a2 * inv;
    }
}

extern "C" void kernel_launch(void* const* d_in, const int* in_sizes, int n_in,
                              void* d_out, int out_size, void* d_ws, size_t ws_size,
                              hipStream_t stream) {
    const float* xyz       = (const float*)d_in[0];
    const float* intensity = (const float*)d_in[1];
    const int*   indices   = (const int*)d_in[2];
    const float* w1        = (const float*)d_in[3];
    const float* b1        = (const float*)d_in[4];
    const float* gamma_    = (const float*)d_in[5];
    const float* beta_     = (const float*)d_in[6];
    const float* mean_     = (const float*)d_in[7];
    const float* var_      = (const float*)d_in[8];
    const float* w2        = (const float*)d_in[9];
    const float* b2        = (const float*)d_in[10];
    float* out = (float*)d_out;

    const int points = PB * PN;                        // 131072
    const size_t rec_bytes = (size_t)points * 16;      // 2 MiB
    const size_t need = rec_bytes + 64;                // + constants

    if (ws_size >= need) {
        uint4* packed = (uint4*)d_ws;
        float* cst = (float*)((char*)d_ws + rec_bytes);
        sa_pack<<<points / 256, 256, 0, stream>>>(xyz, intensity, packed,
                                                  w1, b1, gamma_, beta_, mean_,
                                                  var_, w2, b2, cst);
        // 4 lanes per point: total lanes = points*4
        sa_main4<<<(points * 4) / 256, 256, 0, stream>>>(packed, indices, cst, out);
    } else {
        sa_fallback<<<points / 8, 256, 0, stream>>>(xyz, intensity, indices, w1, b1,
                                                    gamma_, beta_, mean_, var_, w2, b2, out);
    }
}

// Round 5
// 107.058 us; speedup vs baseline: 1.1708x; 1.1708x over previous
//
#include <hip/hip_runtime.h>
#include <hip/hip_fp16.h>
#include <math.h>

// Problem constants (reference: B=8, N=16384, K=32)
#define PB 8
#define PN 16384
#define PK 32
#define PEPS 1e-5f
#define HALF_N 8192   // N/2 points staged in LDS per pass

// ---------------- pre-pass: pack xyz + intensity into 16B fp16 records -----
// packed[b*N+n] = halves {x, y, z, 0, i0, i1, i2, 0}   (one uint4)
// Thread 0 additionally folds BN into affine constants at cst[0..15].
__global__ __launch_bounds__(256) void sa_pack(
    const float* __restrict__ xyz,        // [B,N,3]
    const float* __restrict__ intensity,  // [B,3,N]
    uint4* __restrict__ packed,           // [B*N]
    const float* __restrict__ w1, const float* __restrict__ b1,
    const float* __restrict__ gamma_, const float* __restrict__ beta_,
    const float* __restrict__ mean_, const float* __restrict__ var_,
    const float* __restrict__ w2, const float* __restrict__ b2,
    float* __restrict__ cst)              // [16]
{
    const int t = blockIdx.x * 256 + threadIdx.x;   // 0..B*N-1
    const int b = t >> 14;                          // N = 2^14
    const int n = t & (PN - 1);
    const float x = xyz[(long)t * 3 + 0];
    const float y = xyz[(long)t * 3 + 1];
    const float z = xyz[(long)t * 3 + 2];
    const float* ib = intensity + (long)b * 3 * PN;
    const float i0 = ib[0 * PN + n];
    const float i1 = ib[1 * PN + n];
    const float i2 = ib[2 * PN + n];

    union { __half2 h2[4]; uint4 u; } rec;
    rec.h2[0] = __halves2half2(__float2half_rn(x), __float2half_rn(y));
    rec.h2[1] = __halves2half2(__float2half_rn(z), __float2half_rn(0.f));
    rec.h2[2] = __halves2half2(__float2half_rn(i0), __float2half_rn(i1));
    rec.h2[3] = __halves2half2(__float2half_rn(i2), __float2half_rn(0.f));
    packed[t] = rec.u;

    if (t == 0) {
        for (int o = 0; o < 3; ++o) {
            const float sc = gamma_[o] * rsqrtf(var_[o] + PEPS);
            for (int c = 0; c < 3; ++c) cst[o * 3 + c] = w1[o * 3 + c] * sc;
            cst[9 + o]  = (b1[o] - mean_[o]) * sc + beta_[o];
            cst[12 + o] = w2[o];
        }
        cst[15] = b2[0];
    }
}

// ---------------- main: thread = point, neighbors gathered from LDS --------
// Block = 512 threads = 512 points; 256 blocks = 1 WG/CU (LDS-pinned).
// Each block covers points within ONE batch (16384 % 512 == 0), stages the
// batch's records in two 128KB-total LDS halves, and accumulates the softmax
// sums associatively across halves (no max-subtraction needed: logits are
// bounded by the tiny folded weights).
__global__ __launch_bounds__(512, 1) void sa_lds(
    const uint4* __restrict__ packed,     // [B*N] fp16 records
    const int*   __restrict__ indices,    // [B,N,K]
    const float* __restrict__ cst,        // [16] folded constants
    float* __restrict__ out)              // [B,3,N]
{
    __shared__ uint2 sXYZ[HALF_N];   // 64 KiB: {x,y | z,pad} fp16
    __shared__ uint2 sINT[HALF_N];   // 64 KiB: {i0,i1 | i2,pad} fp16

    const int tid = threadIdx.x;
    const int q   = blockIdx.x * 512 + tid;   // point id
    const int b   = q >> 14;
    const int n   = q & (PN - 1);

    // folded constants (uniform -> scalar loads)
    const float A00 = cst[0], A01 = cst[1], A02 = cst[2];
    const float A10 = cst[3], A11 = cst[4], A12 = cst[5];
    const float A20 = cst[6], A21 = cst[7], A22 = cst[8];
    const float d0 = cst[9], d1 = cst[10], d2 = cst[11];
    const float w0 = cst[12], w1v = cst[13], w2v = cst[14];
    const float bias2 = cst[15];

    // center record (coalesced)
    const uint4 crec = packed[q];
    const float2 cxy = __half22float2(*(const __half2*)&crec.x);
    const float  cz  = __half2float(*(const __half*)&crec.y);

    // all 32 neighbor indices into registers (8 x int4 per thread)
    int idxs[32];
    const int4* ip = (const int4*)(indices + (size_t)q * PK);
#pragma unroll
    for (int j = 0; j < 8; ++j) {
        const int4 v = ip[j];
        idxs[4 * j + 0] = v.x; idxs[4 * j + 1] = v.y;
        idxs[4 * j + 2] = v.z; idxs[4 * j + 3] = v.w;
    }

    const uint4* pb = packed + ((size_t)b << 14);   // batch base

    float s = 0.f, a0 = 0.f, a1 = 0.f, a2 = 0.f;

    for (int h = 0; h < 2; ++h) {
        __syncthreads();   // protect previous half's readers before restage
        // cooperative stage of half h: 8192 records, 16 per thread, coalesced
#pragma unroll
        for (int j = 0; j < 16; ++j) {
            const int r = tid + j * 512;
            const uint4 rec = pb[h * HALF_N + r];
            sXYZ[r] = make_uint2(rec.x, rec.y);
            sINT[r] = make_uint2(rec.z, rec.w);
        }
        __syncthreads();

#pragma unroll
        for (int k = 0; k < PK; ++k) {
            const int idx = idxs[k];
            if ((idx >> 13) == h) {          // neighbor lives in this half
                const int local = idx & (HALF_N - 1);
                const uint2 xz = sXYZ[local];
                const uint2 it = sINT[local];

                const float2 nxy  = __half22float2(*(const __half2*)&xz.x);
                const float  nz   = __half2float(*(const __half*)&xz.y);
                const float2 ni01 = __half22float2(*(const __half2*)&it.x);
                const float  ni2  = __half2float(*(const __half*)&it.y);

                const float px = nxy.x - cxy.x;
                const float py = nxy.y - cxy.y;
                const float pz = nz - cz;

                const float g0 = __expf(-2.f * px * px);
                const float g1 = __expf(-2.f * py * py);
                const float g2 = __expf(-2.f * pz * pz);

                float h0 = fmaf(A00, g0, fmaf(A01, g1, fmaf(A02, g2, d0)));
                float h1 = fmaf(A10, g0, fmaf(A11, g1, fmaf(A12, g2, d1)));
                float h2 = fmaf(A20, g0, fmaf(A21, g1, fmaf(A22, g2, d2)));
                h0 = fmaxf(h0, 0.f); h1 = fmaxf(h1, 0.f); h2 = fmaxf(h2, 0.f);
                const float logit = fmaf(w0, h0, fmaf(w1v, h1, fmaf(w2v, h2, bias2)));

                const float e = __expf(logit);
                s += e;
                a0 = fmaf(e, ni01.x, a0);
                a1 = fmaf(e, ni01.y, a1);
                a2 = fmaf(e, ni2,    a2);
            }
        }
    }

    // per-thread outputs; thread-contiguous n -> coalesced stores
    const float inv = 1.f / s;
    float* ob = out + (size_t)b * 3 * PN;
    ob[0 * PN + n] = a0 * inv;
    ob[1 * PN + n] = a1 * inv;
    ob[2 * PN + n] = a2 * inv;
}

// ---------------- fallback (no workspace): round-1 kernel -----------------
__global__ __launch_bounds__(256) void sa_fallback(
    const float* __restrict__ xyz, const float* __restrict__ intensity,
    const int* __restrict__ indices,
    const float* __restrict__ w1, const float* __restrict__ b1,
    const float* __restrict__ gamma_, const float* __restrict__ beta_,
    const float* __restrict__ mean_, const float* __restrict__ var_,
    const float* __restrict__ w2, const float* __restrict__ b2,
    float* __restrict__ out)
{
    const int lane = threadIdx.x & 31;
    const int grp  = threadIdx.x >> 5;
    const long ng  = (long)blockIdx.x * 8 + grp;
    const int b = (int)(ng >> 14);
    const int n = (int)(ng & (PN - 1));

    float A[3][3], d[3], wv[3];
#pragma unroll
    for (int o = 0; o < 3; ++o) {
        const float sc = gamma_[o] * rsqrtf(var_[o] + PEPS);
#pragma unroll
        for (int c = 0; c < 3; ++c) A[o][c] = w1[o * 3 + c] * sc;
        d[o]  = (b1[o] - mean_[o]) * sc + beta_[o];
        wv[o] = w2[o];
    }
    const float bias2 = b2[0];
    const long bn = (long)b * PN + n;
    const float cx = xyz[bn * 3 + 0], cy = xyz[bn * 3 + 1], cz = xyz[bn * 3 + 2];
    const int idx = indices[bn * PK + lane];
    const long bi = (long)b * PN + idx;
    const float px = xyz[bi * 3 + 0] - cx;
    const float py = xyz[bi * 3 + 1] - cy;
    const float pz = xyz[bi * 3 + 2] - cz;
    const float g0 = __expf(-2.f * px * px);
    const float g1 = __expf(-2.f * py * py);
    const float g2 = __expf(-2.f * pz * pz);
    float logit = bias2;
#pragma unroll
    for (int o = 0; o < 3; ++o) {
        float h = A[o][0] * g0 + A[o][1] * g1 + A[o][2] * g2 + d[o];
        h = fmaxf(h, 0.f);
        logit = fmaf(wv[o], h, logit);
    }
    float m = logit;
#pragma unroll
    for (int s = 16; s > 0; s >>= 1) m = fmaxf(m, __shfl_xor(m, s, 64));
    const float e = __expf(logit - m);
    const float* ib = intensity + (long)b * 3 * PN;
    float ssum = e;
    float a0 = e * ib[0 * PN + idx];
    float a1 = e * ib[1 * PN + idx];
    float a2 = e * ib[2 * PN + idx];
#pragma unroll
    for (int s = 16; s > 0; s >>= 1) {
        ssum += __shfl_xor(ssum, s, 64);
        a0 += __shfl_xor(a0, s, 64);
        a1 += __shfl_xor(a1, s, 64);
        a2 += __shfl_xor(a2, s, 64);
    }
    if (lane == 0) {
        const float inv = 1.f / ssum;
        float* ob = out + (long)b * 3 * PN;
        ob[0 * PN + n] = a0 * inv;
        ob[1 * PN + n] = a1 * inv;
        ob[2 * PN + n] = a2 * inv;
    }
}

extern "C" void kernel_launch(void* const* d_in, const int* in_sizes, int n_in,
                              void* d_out, int out_size, void* d_ws, size_t ws_size,
                              hipStream_t stream) {
    const float* xyz       = (const float*)d_in[0];
    const float* intensity = (const float*)d_in[1];
    const int*   indices   = (const int*)d_in[2];
    const float* w1        = (const float*)d_in[3];
    const float* b1        = (const float*)d_in[4];
    const float* gamma_    = (const float*)d_in[5];
    const float* beta_     = (const float*)d_in[6];
    const float* mean_     = (const float*)d_in[7];
    const float* var_      = (const float*)d_in[8];
    const float* w2        = (const float*)d_in[9];
    const float* b2        = (const float*)d_in[10];
    float* out = (float*)d_out;

    const int points = PB * PN;                        // 131072
    const size_t rec_bytes = (size_t)points * 16;      // 2 MiB
    const size_t need = rec_bytes + 64;                // + constants

    if (ws_size >= need) {
        uint4* packed = (uint4*)d_ws;
        float* cst = (float*)((char*)d_ws + rec_bytes);
        sa_pack<<<points / 256, 256, 0, stream>>>(xyz, intensity, packed,
                                                  w1, b1, gamma_, beta_, mean_,
                                                  var_, w2, b2, cst);
        // thread = point: 256 blocks x 512 threads, 1 WG/CU (128 KiB LDS)
        sa_lds<<<points / 512, 512, 0, stream>>>(packed, indices, cst, out);
    } else {
        sa_fallback<<<points / 8, 256, 0, stream>>>(xyz, intensity, indices, w1, b1,
                                                    gamma_, beta_, mean_, var_, w2, b2, out);
    }
}

// Round 6
// 101.938 us; speedup vs baseline: 1.2296x; 1.0502x over previous
//
#include <hip/hip_runtime.h>
#include <hip/hip_fp16.h>
#include <math.h>

// Problem constants (reference: B=8, N=16384, K=32)
#define PB 8
#define PN 16384
#define PK 32
#define PEPS 1e-5f

// ---------------- pre-pass: pack xyz and intensity into 8B fp16 records ----
// pxyz[b*N+n] = {h2(x,y), h2(z,0)}   pint[b*N+n] = {h2(i0,i1), h2(i2,0)}
// Thread 0 additionally folds BN into affine constants at cst[0..15].
__global__ __launch_bounds__(256) void sa_pack(
    const float* __restrict__ xyz,        // [B,N,3]
    const float* __restrict__ intensity,  // [B,3,N]
    uint2* __restrict__ pxyz,             // [B*N]
    uint2* __restrict__ pint,             // [B*N]
    const float* __restrict__ w1, const float* __restrict__ b1,
    const float* __restrict__ gamma_, const float* __restrict__ beta_,
    const float* __restrict__ mean_, const float* __restrict__ var_,
    const float* __restrict__ w2, const float* __restrict__ b2,
    float* __restrict__ cst)              // [16]
{
    const int t = blockIdx.x * 256 + threadIdx.x;   // 0..B*N-1
    const int b = t >> 14;                          // N = 2^14
    const int n = t & (PN - 1);
    const float x = xyz[(long)t * 3 + 0];
    const float y = xyz[(long)t * 3 + 1];
    const float z = xyz[(long)t * 3 + 2];
    const float* ib = intensity + (long)b * 3 * PN;
    const float i0 = ib[0 * PN + n];
    const float i1 = ib[1 * PN + n];
    const float i2 = ib[2 * PN + n];

    union { __half2 h2[2]; uint2 u; } rx, ri;
    rx.h2[0] = __halves2half2(__float2half_rn(x), __float2half_rn(y));
    rx.h2[1] = __halves2half2(__float2half_rn(z), __float2half_rn(0.f));
    ri.h2[0] = __halves2half2(__float2half_rn(i0), __float2half_rn(i1));
    ri.h2[1] = __halves2half2(__float2half_rn(i2), __float2half_rn(0.f));
    pxyz[t] = rx.u;
    pint[t] = ri.u;

    if (t == 0) {
        for (int o = 0; o < 3; ++o) {
            const float sc = gamma_[o] * rsqrtf(var_[o] + PEPS);
            for (int c = 0; c < 3; ++c) cst[o * 3 + c] = w1[o * 3 + c] * sc;
            cst[9 + o]  = (b1[o] - mean_[o]) * sc + beta_[o];
            cst[12 + o] = w2[o];
        }
        cst[15] = b2[0];
    }
}

// ---------------- main: thread = point; two operand phases over one LDS ----
// Block = 512 threads = 512 points within ONE batch (16384 % 512 == 0).
// Phase 1: stage the WHOLE batch's xyz (128 KiB), compute e_k for all 32
//          neighbors straight-line (no guards), accumulate denominator.
// Phase 2: restage the same buffer with intensity, accumulate sum e_k*i_k.
// Logits are bounded by the tiny folded weights -> no max-subtraction.
__global__ __launch_bounds__(512, 1) void sa_lds2(
    const uint2* __restrict__ pxyz,       // [B*N] fp16 xyz records
    const uint2* __restrict__ pint,       // [B*N] fp16 intensity records
    const int*   __restrict__ indices,    // [B,N,K]
    const float* __restrict__ cst,        // [16] folded constants
    float* __restrict__ out)              // [B,3,N]
{
    __shared__ uint4 sbuf[PN / 2];        // 128 KiB, holds one full operand

    const int tid = threadIdx.x;
    const int q   = blockIdx.x * 512 + tid;   // point id
    const int b   = q >> 14;
    const int n   = q & (PN - 1);

    // folded constants (uniform -> scalar loads)
    const float A00 = cst[0], A01 = cst[1], A02 = cst[2];
    const float A10 = cst[3], A11 = cst[4], A12 = cst[5];
    const float A20 = cst[6], A21 = cst[7], A22 = cst[8];
    const float d0 = cst[9], d1 = cst[10], d2 = cst[11];
    const float w0 = cst[12], w1v = cst[13], w2v = cst[14];
    const float bias2 = cst[15];

    // center xyz (coalesced)
    const uint2 crec = pxyz[q];
    const float2 cxy = __half22float2(*(const __half2*)&crec.x);
    const float  cz  = __half2float(*(const __half*)&crec.y);

    // all 32 neighbor indices into registers (coalesced int4 loads)
    int idxs[32];
    const int4* ip = (const int4*)(indices + (size_t)q * PK);
#pragma unroll
    for (int j = 0; j < 8; ++j) {
        const int4 v = ip[j];
        idxs[4 * j + 0] = v.x; idxs[4 * j + 1] = v.y;
        idxs[4 * j + 2] = v.z; idxs[4 * j + 3] = v.w;
    }

    const uint2* sx = (const uint2*)sbuf;

    // ---- phase 1: stage batch xyz, compute all e_k ----
    {
        const uint4* src = (const uint4*)(pxyz + ((size_t)b << 14));
#pragma unroll
        for (int j = 0; j < 16; ++j) {
            const int r = tid + j * 512;
            sbuf[r] = src[r];
        }
    }
    __syncthreads();

    float ev[32];
    float s = 0.f;
#pragma unroll
    for (int k = 0; k < PK; ++k) {
        const uint2 xz = sx[idxs[k]];
        const float2 nxy = __half22float2(*(const __half2*)&xz.x);
        const float  nz  = __half2float(*(const __half*)&xz.y);

        const float px = nxy.x - cxy.x;
        const float py = nxy.y - cxy.y;
        const float pz = nz - cz;

        const float g0 = __expf(-2.f * px * px);
        const float g1 = __expf(-2.f * py * py);
        const float g2 = __expf(-2.f * pz * pz);

        float h0 = fmaf(A00, g0, fmaf(A01, g1, fmaf(A02, g2, d0)));
        float h1 = fmaf(A10, g0, fmaf(A11, g1, fmaf(A12, g2, d1)));
        float h2 = fmaf(A20, g0, fmaf(A21, g1, fmaf(A22, g2, d2)));
        h0 = fmaxf(h0, 0.f); h1 = fmaxf(h1, 0.f); h2 = fmaxf(h2, 0.f);
        const float logit = fmaf(w0, h0, fmaf(w1v, h1, fmaf(w2v, h2, bias2)));

        const float e = __expf(logit);
        ev[k] = e;
        s += e;
    }

    // ---- phase 2: restage with intensity, weighted accumulate ----
    __syncthreads();   // everyone done reading xyz
    {
        const uint4* src = (const uint4*)(pint + ((size_t)b << 14));
#pragma unroll
        for (int j = 0; j < 16; ++j) {
            const int r = tid + j * 512;
            sbuf[r] = src[r];
        }
    }
    __syncthreads();

    float a0 = 0.f, a1 = 0.f, a2 = 0.f;
#pragma unroll
    for (int k = 0; k < PK; ++k) {
        const uint2 it = sx[idxs[k]];
        const float2 i01 = __half22float2(*(const __half2*)&it.x);
        const float  i2  = __half2float(*(const __half*)&it.y);
        const float e = ev[k];
        a0 = fmaf(e, i01.x, a0);
        a1 = fmaf(e, i01.y, a1);
        a2 = fmaf(e, i2,    a2);
    }

    // coalesced per-channel stores
    const float inv = 1.f / s;
    float* ob = out + (size_t)b * 3 * PN;
    ob[0 * PN + n] = a0 * inv;
    ob[1 * PN + n] = a1 * inv;
    ob[2 * PN + n] = a2 * inv;
}

// ---------------- fallback (no workspace): round-1 kernel -----------------
__global__ __launch_bounds__(256) void sa_fallback(
    const float* __restrict__ xyz, const float* __restrict__ intensity,
    const int* __restrict__ indices,
    const float* __restrict__ w1, const float* __restrict__ b1,
    const float* __restrict__ gamma_, const float* __restrict__ beta_,
    const float* __restrict__ mean_, const float* __restrict__ var_,
    const float* __restrict__ w2, const float* __restrict__ b2,
    float* __restrict__ out)
{
    const int lane = threadIdx.x & 31;
    const int grp  = threadIdx.x >> 5;
    const long ng  = (long)blockIdx.x * 8 + grp;
    const int b = (int)(ng >> 14);
    const int n = (int)(ng & (PN - 1));

    float A[3][3], d[3], wv[3];
#pragma unroll
    for (int o = 0; o < 3; ++o) {
        const float sc = gamma_[o] * rsqrtf(var_[o] + PEPS);
#pragma unroll
        for (int c = 0; c < 3; ++c) A[o][c] = w1[o * 3 + c] * sc;
        d[o]  = (b1[o] - mean_[o]) * sc + beta_[o];
        wv[o] = w2[o];
    }
    const float bias2 = b2[0];
    const long bn = (long)b * PN + n;
    const float cx = xyz[bn * 3 + 0], cy = xyz[bn * 3 + 1], cz = xyz[bn * 3 + 2];
    const int idx = indices[bn * PK + lane];
    const long bi = (long)b * PN + idx;
    const float px = xyz[bi * 3 + 0] - cx;
    const float py = xyz[bi * 3 + 1] - cy;
    const float pz = xyz[bi * 3 + 2] - cz;
    const float g0 = __expf(-2.f * px * px);
    const float g1 = __expf(-2.f * py * py);
    const float g2 = __expf(-2.f * pz * pz);
    float logit = bias2;
#pragma unroll
    for (int o = 0; o < 3; ++o) {
        float h = A[o][0] * g0 + A[o][1] * g1 + A[o][2] * g2 + d[o];
        h = fmaxf(h, 0.f);
        logit = fmaf(wv[o], h, logit);
    }
    float m = logit;
#pragma unroll
    for (int s = 16; s > 0; s >>= 1) m = fmaxf(m, __shfl_xor(m, s, 64));
    const float e = __expf(logit - m);
    const float* ib = intensity + (long)b * 3 * PN;
    float ssum = e;
    float a0 = e * ib[0 * PN + idx];
    float a1 = e * ib[1 * PN + idx];
    float a2 = e * ib[2 * PN + idx];
#pragma unroll
    for (int s = 16; s > 0; s >>= 1) {
        ssum += __shfl_xor(ssum, s, 64);
        a0 += __shfl_xor(a0, s, 64);
        a1 += __shfl_xor(a1, s, 64);
        a2 += __shfl_xor(a2, s, 64);
    }
    if (lane == 0) {
        const float inv = 1.f / ssum;
        float* ob = out + (long)b * 3 * PN;
        ob[0 * PN + n] = a0 * inv;
        ob[1 * PN + n] = a1 * inv;
        ob[2 * PN + n] = a2 * inv;
    }
}

extern "C" void kernel_launch(void* const* d_in, const int* in_sizes, int n_in,
                              void* d_out, int out_size, void* d_ws, size_t ws_size,
                              hipStream_t stream) {
    const float* xyz       = (const float*)d_in[0];
    const float* intensity = (const float*)d_in[1];
    const int*   indices   = (const int*)d_in[2];
    const float* w1        = (const float*)d_in[3];
    const float* b1        = (const float*)d_in[4];
    const float* gamma_    = (const float*)d_in[5];
    const float* beta_     = (const float*)d_in[6];
    const float* mean_     = (const float*)d_in[7];
    const float* var_      = (const float*)d_in[8];
    const float* w2        = (const float*)d_in[9];
    const float* b2        = (const float*)d_in[10];
    float* out = (float*)d_out;

    const int points = PB * PN;                         // 131072
    const size_t arr_bytes = (size_t)points * 8;        // 1 MiB each
    const size_t need = 2 * arr_bytes + 64;             // pxyz + pint + cst

    if (ws_size >= need) {
        uint2* pxyz = (uint2*)d_ws;
        uint2* pint = (uint2*)((char*)d_ws + arr_bytes);
        float* cst  = (float*)((char*)d_ws + 2 * arr_bytes);
        sa_pack<<<points / 256, 256, 0, stream>>>(xyz, intensity, pxyz, pint,
                                                  w1, b1, gamma_, beta_, mean_,
                                                  var_, w2, b2, cst);
        // thread = point: 256 blocks x 512 threads, 1 WG/CU (128 KiB LDS)
        sa_lds2<<<points / 512, 512, 0, stream>>>(pxyz, pint, indices, cst, out);
    } else {
        sa_fallback<<<points / 8, 256, 0, stream>>>(xyz, intensity, indices, w1, b1,
                                                    gamma_, beta_, mean_, var_, w2, b2, out);
    }
}

// Round 7
// 99.859 us; speedup vs baseline: 1.2552x; 1.0208x over previous
//
#include <hip/hip_runtime.h>
#include <hip/hip_fp16.h>
#include <math.h>

// Problem constants (reference: B=8, N=16384, K=32)
#define PB 8
#define PN 16384
#define PK 32
#define PEPS 1e-5f

// pack three floats into {h2(a,b), h2(c,0)}
__device__ __forceinline__ uint2 pack3(float a, float b, float c) {
    union { __half2 h2[2]; uint2 u; } r;
    r.h2[0] = __halves2half2(__float2half_rn(a), __float2half_rn(b));
    r.h2[1] = __halves2half2(__float2half_rn(c), __float2half_rn(0.f));
    return r.u;
}

// Single fused kernel. Block = 512 threads = 512 points of ONE batch
// (16384 % 512 == 0); 256 blocks = 1 WG/CU (128 KiB LDS).
// Phase 1: stage whole batch xyz (fp32->fp16, 128 KiB LDS), compute all 32
//          softmax numerators e_k per thread straight-line.
// Phase 2: restage same LDS with intensity (prefetched into registers during
//          phase 1), accumulate sum e_k * i_k.
// Logits are bounded by the tiny folded weights -> no max-subtraction needed
// (validated rounds 5/6).
__global__ __launch_bounds__(512, 1) void sa_fused(
    const float* __restrict__ xyz,        // [B,N,3]
    const float* __restrict__ intensity,  // [B,3,N]
    const int*   __restrict__ indices,    // [B,N,K]
    const float* __restrict__ w1, const float* __restrict__ b1,
    const float* __restrict__ gamma_, const float* __restrict__ beta_,
    const float* __restrict__ mean_, const float* __restrict__ var_,
    const float* __restrict__ w2, const float* __restrict__ b2,
    float* __restrict__ out)              // [B,3,N]
{
    __shared__ uint4 sbuf[PN / 2];        // 128 KiB, one operand for the batch
    const uint2* sx = (const uint2*)sbuf;

    const int tid = threadIdx.x;
    const int q   = blockIdx.x * 512 + tid;   // point id
    const int b   = q >> 14;                  // N = 2^14
    const int n   = q & (PN - 1);

    // fold BN into affine (uniform VALU, once per thread)
    const float sc0 = gamma_[0] * rsqrtf(var_[0] + PEPS);
    const float sc1 = gamma_[1] * rsqrtf(var_[1] + PEPS);
    const float sc2 = gamma_[2] * rsqrtf(var_[2] + PEPS);
    const float A00 = w1[0] * sc0, A01 = w1[1] * sc0, A02 = w1[2] * sc0;
    const float A10 = w1[3] * sc1, A11 = w1[4] * sc1, A12 = w1[5] * sc1;
    const float A20 = w1[6] * sc2, A21 = w1[7] * sc2, A22 = w1[8] * sc2;
    const float d0 = (b1[0] - mean_[0]) * sc0 + beta_[0];
    const float d1 = (b1[1] - mean_[1]) * sc1 + beta_[1];
    const float d2 = (b1[2] - mean_[2]) * sc2 + beta_[2];
    const float w0 = w2[0], w1v = w2[1], w2v = w2[2];
    const float bias2 = b2[0];

    // center xyz in fp32 (exact)
    const float cx = xyz[3 * (size_t)q + 0];
    const float cy = xyz[3 * (size_t)q + 1];
    const float cz = xyz[3 * (size_t)q + 2];

    // all 32 neighbor indices (coalesced int4 loads)
    int idxs[32];
    {
        const int4* ip = (const int4*)(indices + (size_t)q * PK);
#pragma unroll
        for (int j = 0; j < 8; ++j) {
            const int4 v = ip[j];
            idxs[4 * j + 0] = v.x; idxs[4 * j + 1] = v.y;
            idxs[4 * j + 2] = v.z; idxs[4 * j + 3] = v.w;
        }
    }

    // ---- stage 1: batch xyz fp32 -> fp16 LDS (3 float4 = 4 points) ----
    {
        const float4* xv = (const float4*)(xyz + (size_t)b * PN * 3);
#pragma unroll
        for (int j = 0; j < 8; ++j) {
            const int m = tid + j * 512;          // 0..4095 (4 points each)
            const float4 f0 = xv[3 * m + 0];
            const float4 f1 = xv[3 * m + 1];
            const float4 f2 = xv[3 * m + 2];
            union { uint2 u2[4]; uint4 u4[2]; } pk;
            pk.u2[0] = pack3(f0.x, f0.y, f0.z);
            pk.u2[1] = pack3(f0.w, f1.x, f1.y);
            pk.u2[2] = pack3(f1.z, f1.w, f2.x);
            pk.u2[3] = pack3(f2.y, f2.z, f2.w);
            sbuf[2 * m + 0] = pk.u4[0];
            sbuf[2 * m + 1] = pk.u4[1];
        }
    }
    __syncthreads();

    // ---- prefetch intensity rows 0,1 (issued before phase-1 compute so the
    //      global latency overlaps the gather/exp work) ----
    const float4* iv = (const float4*)(intensity + (size_t)b * 3 * PN);
    float4 pf[16];
#pragma unroll
    for (int j = 0; j < 16; ++j) pf[j] = iv[tid + j * 512];   // rows 0,1

    // ---- phase 1: all 32 e_k, straight-line, no guards ----
    float ev[32];
    float s = 0.f;
#pragma unroll
    for (int k = 0; k < PK; ++k) {
        const uint2 xz = sx[idxs[k]];
        const float2 nxy = __half22float2(*(const __half2*)&xz.x);
        const float  nz  = __half2float(*(const __half*)&xz.y);

        const float px = nxy.x - cx;
        const float py = nxy.y - cy;
        const float pz = nz - cz;

        const float g0 = __expf(-2.f * px * px);
        const float g1 = __expf(-2.f * py * py);
        const float g2 = __expf(-2.f * pz * pz);

        float h0 = fmaf(A00, g0, fmaf(A01, g1, fmaf(A02, g2, d0)));
        float h1 = fmaf(A10, g0, fmaf(A11, g1, fmaf(A12, g2, d1)));
        float h2 = fmaf(A20, g0, fmaf(A21, g1, fmaf(A22, g2, d2)));
        h0 = fmaxf(h0, 0.f); h1 = fmaxf(h1, 0.f); h2 = fmaxf(h2, 0.f);
        const float logit = fmaf(w0, h0, fmaf(w1v, h1, fmaf(w2v, h2, bias2)));

        const float e = __expf(logit);
        ev[k] = e;
        s += e;
    }

    // row 2 of intensity (short exposure; arrives during barrier drain)
    float4 pr2[8];
#pragma unroll
    for (int j = 0; j < 8; ++j) pr2[j] = iv[8192 + tid + j * 512];

    __syncthreads();   // everyone done reading xyz from LDS

    // ---- stage 2: intensity (from prefetched regs) -> LDS ----
#pragma unroll
    for (int j = 0; j < 8; ++j) {
        const int m = tid + j * 512;
        const float4 f0 = pf[j];        // i0 for points 4m..4m+3
        const float4 f1 = pf[j + 8];    // i1
        const float4 f2 = pr2[j];       // i2
        union { uint2 u2[4]; uint4 u4[2]; } pk;
        pk.u2[0] = pack3(f0.x, f1.x, f2.x);
        pk.u2[1] = pack3(f0.y, f1.y, f2.y);
        pk.u2[2] = pack3(f0.z, f1.z, f2.z);
        pk.u2[3] = pack3(f0.w, f1.w, f2.w);
        sbuf[2 * m + 0] = pk.u4[0];
        sbuf[2 * m + 1] = pk.u4[1];
    }
    __syncthreads();

    // ---- phase 2: weighted intensity accumulate ----
    float a0 = 0.f, a1 = 0.f, a2 = 0.f;
#pragma unroll
    for (int k = 0; k < PK; ++k) {
        const uint2 it = sx[idxs[k]];
        const float2 i01 = __half22float2(*(const __half2*)&it.x);
        const float  i2v = __half2float(*(const __half*)&it.y);
        const float e = ev[k];
        a0 = fmaf(e, i01.x, a0);
        a1 = fmaf(e, i01.y, a1);
        a2 = fmaf(e, i2v,  a2);
    }

    // coalesced per-channel stores
    const float inv = 1.f / s;
    float* ob = out + (size_t)b * 3 * PN;
    ob[0 * PN + n] = a0 * inv;
    ob[1 * PN + n] = a1 * inv;
    ob[2 * PN + n] = a2 * inv;
}

extern "C" void kernel_launch(void* const* d_in, const int* in_sizes, int n_in,
                              void* d_out, int out_size, void* d_ws, size_t ws_size,
                              hipStream_t stream) {
    const float* xyz       = (const float*)d_in[0];
    const float* intensity = (const float*)d_in[1];
    const int*   indices   = (const int*)d_in[2];
    const float* w1        = (const float*)d_in[3];
    const float* b1        = (const float*)d_in[4];
    const float* gamma_    = (const float*)d_in[5];
    const float* beta_     = (const float*)d_in[6];
    const float* mean_     = (const float*)d_in[7];
    const float* var_      = (const float*)d_in[8];
    const float* w2        = (const float*)d_in[9];
    const float* b2        = (const float*)d_in[10];
    float* out = (float*)d_out;

    const int points = PB * PN;   // 131072
    // single fused kernel, no workspace: 256 blocks x 512 threads (1 WG/CU)
    sa_fused<<<points / 512, 512, 0, stream>>>(xyz, intensity, indices,
                                               w1, b1, gamma_, beta_, mean_,
                                               var_, w2, b2, out);
}